// Round 12
// baseline (403.745 us; speedup 1.0000x reference)
//
#include <hip/hip_runtime.h>
#include <hip/hip_bf16.h>
#include <stdint.h>

typedef __attribute__((ext_vector_type(8)))  __bf16 bf16x8;
typedef __attribute__((ext_vector_type(4)))  float  f32x4;
typedef __attribute__((ext_vector_type(16))) float  f32x16;
typedef __hip_bfloat16 bf16_t;

#define T_SEQ 2048
#define D_MODEL 1024
#define N_HEADS 16
#define N_KV 4
#define HD 64
#define LDQKV 1536
#define KDIM 1024

// Convert 16 consecutive fp32 (4x float4) -> 16 bf16 (2x int4)
__device__ inline void cvt16(const float4* __restrict__ g, int4* __restrict__ s) {
  float4 v0 = g[0], v1 = g[1], v2 = g[2], v3 = g[3];
  union { int4 i[2]; __hip_bfloat162 h[8]; } u;
  u.h[0] = __float22bfloat162_rn(make_float2(v0.x, v0.y));
  u.h[1] = __float22bfloat162_rn(make_float2(v0.z, v0.w));
  u.h[2] = __float22bfloat162_rn(make_float2(v1.x, v1.y));
  u.h[3] = __float22bfloat162_rn(make_float2(v1.z, v1.w));
  u.h[4] = __float22bfloat162_rn(make_float2(v2.x, v2.y));
  u.h[5] = __float22bfloat162_rn(make_float2(v2.z, v2.w));
  u.h[6] = __float22bfloat162_rn(make_float2(v3.x, v3.y));
  u.h[7] = __float22bfloat162_rn(make_float2(v3.z, v3.w));
  s[0] = u.i[0]; s[1] = u.i[1];
}

__device__ inline void storeC(bf16_t* p, float v) { *p = __float2bfloat16(v); }
__device__ inline void storeC(float* p, float v) { *p = v; }

// v_permlane32_swap_b32 vdst, vsrc: after plswap(a,b): a={a_L,b_L}, b={a_U,b_U}
__device__ inline void plswap(unsigned& a, unsigned& b) {
  asm volatile("v_permlane32_swap_b32 %0, %1" : "+v"(a), "+v"(b));
}

// HW transcendental exp2 (input already in log2 domain)
__device__ inline float fexp2(float x) {
  float r; asm("v_exp_f32 %0, %1" : "=v"(r) : "v"(x)); return r;
}
// HW packed fp32->bf16 (T12 recipe; no builtin on gfx950)
__device__ inline unsigned cvtpk(float lo, float hi) {
  unsigned r; asm("v_cvt_pk_bf16_f32 %0, %1, %2" : "=v"(r) : "v"(lo), "v"(hi));
  return r;
}

// async global->LDS, 16B per lane; lds dest must be wave-uniform base.
__device__ inline void gll16(const bf16_t* g, bf16_t* l) {
  __builtin_amdgcn_global_load_lds(
      (const __attribute__((address_space(1))) void*)g,
      (__attribute__((address_space(3))) void*)l, 16, 0, 0);
}

// ---------------------------------------------------------------------------
// fp32 -> bf16 bulk convert: thread i handles 16 elements.
// ---------------------------------------------------------------------------
__global__ __launch_bounds__(256) void to_bf16(const float* __restrict__ s,
                                               bf16_t* __restrict__ d,
                                               const int n16) {
  const int i = blockIdx.x * 256 + threadIdx.x;
  if (i < n16) cvt16((const float4*)s + i * 4, (int4*)d + i * 2);
}

// ---------------------------------------------------------------------------
// GEMM bf16 x bf16 (unchanged — passing)
// ---------------------------------------------------------------------------
template <typename CT>
__global__ __launch_bounds__(256) void gemm_bb(
    const bf16_t* __restrict__ A, const bf16_t* __restrict__ W,
    CT* __restrict__ C, const int ldC)
{
  __shared__ bf16_t As[128 * 32];
  __shared__ bf16_t Bs[128 * 32];
  const int tid = threadIdx.x;
  const int lane = tid & 63;
  const int wv = tid >> 6;
  const int wr = wv >> 1, wc = wv & 1;
  const int m0 = blockIdx.y * 128;
  const int n0 = blockIdx.x * 128;

  const int srow = lane >> 2;
  const int scol = (lane & 3) * 8;
  const bf16_t* gA = A + (size_t)(m0 + 32 * wv + srow) * KDIM + scol;
  const bf16_t* gB = W + (size_t)(n0 + 32 * wv + srow) * KDIM + scol;
  bf16_t* lA = As + wv * 1024;
  bf16_t* lB = Bs + wv * 1024;

  f32x4 acc[4][4];
#pragma unroll
  for (int m = 0; m < 4; ++m)
#pragma unroll
    for (int n = 0; n < 4; ++n)
      acc[m][n] = {0.f, 0.f, 0.f, 0.f};

  const int fr = lane & 15;
  const int fq = lane >> 4;

  for (int k0 = 0; k0 < KDIM; k0 += 32) {
    gll16(gA + k0, lA);
    gll16(gA + 16 * KDIM + k0, lA + 512);
    gll16(gB + k0, lB);
    gll16(gB + 16 * KDIM + k0, lB + 512);
    __syncthreads();
    bf16x8 af[4], bfv[4];
#pragma unroll
    for (int m = 0; m < 4; ++m)
      af[m] = *(const bf16x8*)(&As[(wr * 64 + m * 16 + fr) * 32 + fq * 8]);
#pragma unroll
    for (int n = 0; n < 4; ++n)
      bfv[n] = *(const bf16x8*)(&Bs[(wc * 64 + n * 16 + fr) * 32 + fq * 8]);
#pragma unroll
    for (int m = 0; m < 4; ++m)
#pragma unroll
      for (int n = 0; n < 4; ++n)
        acc[m][n] = __builtin_amdgcn_mfma_f32_16x16x32_bf16(af[m], bfv[n],
                                                            acc[m][n], 0, 0, 0);
    __syncthreads();
  }

#pragma unroll
  for (int m = 0; m < 4; ++m)
#pragma unroll
    for (int n = 0; n < 4; ++n)
#pragma unroll
      for (int r = 0; r < 4; ++r) {
        const int row = wr * 64 + m * 16 + fq * 4 + r;
        const int col = wc * 64 + n * 16 + fr;
        storeC(&C[(size_t)(m0 + row) * ldC + n0 + col], acc[m][n][r]);
      }
}

// ---------------------------------------------------------------------------
// RMSNorm + RoPE (unchanged — passing)
// ---------------------------------------------------------------------------
__global__ __launch_bounds__(256) void rms_rope(
    bf16_t* __restrict__ qkv, const float* __restrict__ cosb,
    const float* __restrict__ sinb, const float* __restrict__ qs,
    const float* __restrict__ ks)
{
  const int row = blockIdx.x;
  const int t = row & (T_SEQ - 1);
  const int tid = threadIdx.x;
  const int lane = tid & 63;
  const int wv = tid >> 6;
  const int f = lane & 15;
  const float c = (lane < 32) ? cosb[t * 16 + f] : 0.f;
  const float s = (lane < 32) ? sinb[t * 16 + f] : 0.f;
  for (int hh = wv; hh < 20; hh += 4) {
    const size_t idx = (size_t)row * LDQKV + hh * 64 + lane;
    const float v = __bfloat162float(qkv[idx]);
    float ssum = v * v;
#pragma unroll
    for (int off = 32; off; off >>= 1) ssum += __shfl_xor(ssum, off);
    const float norm = rsqrtf(ssum * (1.f / 64.f) + 1e-6f);
    const float scale = (hh < 16 ? qs : ks)[lane];
    float val = v * norm * scale;
    const float partner = __shfl_xor(val, 16);
    if (lane < 16)      val = val * c - partner * s;
    else if (lane < 32) val = partner * s + val * c;
    qkv[idx] = __float2bfloat16(val);
  }
}

// ---------------------------------------------------------------------------
// V transpose (unchanged — passing)
// ---------------------------------------------------------------------------
__global__ __launch_bounds__(256) void v_transpose(
    const bf16_t* __restrict__ qkv, bf16_t* __restrict__ v_t)
{
  __shared__ bf16_t tile[64 * 72];
  const int g = blockIdx.x;
  const int t0 = blockIdx.y * 64;
  const int tid = threadIdx.x;
  const int i = tid >> 2;
  const int dc = (tid & 3) * 16;
  const bf16_t* src = qkv + (size_t)((g >> 2) * T_SEQ + t0 + i) * LDQKV
                      + 1280 + (g & 3) * HD + dc;
  const int4* gs = (const int4*)src;
  int4 x0 = gs[0], x1 = gs[1];
  int4* st = (int4*)(&tile[i * 72 + dc]);
  st[0] = x0; st[1] = x1;
  __syncthreads();
  union { int4 v[2]; bf16_t h[16]; } u;
#pragma unroll
  for (int j = 0; j < 16; ++j) u.h[j] = tile[(dc + j) * 72 + i];
  int4* dst = (int4*)(v_t + (size_t)(g * HD + i) * T_SEQ + t0 + dc);
  dst[0] = u.v[0]; dst[1] = u.v[1];
}

// ---------------------------------------------------------------------------
// Causal GQA flash attention v9 — ONE WAVE PER BLOCK, barrier-free.
// Block = 64 threads = one 32-row q-strip; grid 4096 (longest strips first).
// Wave stages its own K/V 32-k tile into 8KB LDS (single buffer; DS pipe is
// in-order per wave so read-then-write ordering is safe without barriers).
// Next tile's global loads issue into regs before compute (T14 split).
// HW block scheduler load-balances the uneven strip lengths via the 16-deep
// per-CU queue. Softmax math identical to v8 (passing).
// ---------------------------------------------------------------------------
__global__ __launch_bounds__(64) void attn(
    const bf16_t* __restrict__ qkv, const bf16_t* __restrict__ v_t,
    bf16_t* __restrict__ y)
{
  __shared__ int4 lds[512];       // 8 KB: K 4KB | V 4KB (single buffer)
  const int lane = threadIdx.x;   // 0..63
  const int ql   = lane & 31;
  const int hi   = lane >> 5;
  const int id   = (int)blockIdx.x;   // 0..4095
  const int bh   = id & 63;           // spread bh across consecutive ids
  const int s    = 63 - (id >> 6);    // longest strips dispatch first
  const int b    = bh >> 4, h = bh & 15, kvh = (bh & 15) >> 2;
  const int q_glob = s * 32 + ql;
  const int nt     = s + 1;
  const float SCALE_LOG2 = 0.125f * 1.44269504089f;

  // --- staging: lane covers int4 slots {lane+64j} for K and V tiles ---
  const bf16_t* gKp[4]; const bf16_t* gVp[4];
  int kwi[4], vwi[4];
#pragma unroll
  for (int j = 0; j < 4; ++j) {
    const int slot = lane + 64 * j;
    const int kr = slot >> 3, ks2 = slot & 7;
    gKp[j] = qkv + (size_t)(b * T_SEQ + kr) * LDQKV + 1024 + kvh * HD + ks2 * 8;
    kwi[j] = kr * 8 + (ks2 ^ (kr & 7));
    const int vd = slot >> 2, vs2 = slot & 3;
    gVp[j] = v_t + (size_t)((b * N_KV + kvh) * HD + vd) * T_SEQ + vs2 * 8;
    vwi[j] = 256 + vd * 4 + (vs2 ^ ((vd >> 1) & 3));
  }

  // --- fragment read indices (same swizzle as staging writes) ---
  int kridx[4];
#pragma unroll
  for (int c = 0; c < 4; ++c)
    kridx[c] = ql * 8 + ((2 * c + hi) ^ (ql & 7));
  const int vsw = (ql >> 1) & 3;
  const int v0idx = 256 + ql * 4 + (hi ^ vsw);
  const int v1idx = 256 + ql * 4 + ((2 + hi) ^ vsw);
  const int v2idx = 256 + (ql + 32) * 4 + (hi ^ vsw);
  const int v3idx = 256 + (ql + 32) * 4 + ((2 + hi) ^ vsw);

  // Q fragments, pre-scaled into log2 domain
  const bf16_t* Qrow = qkv + (size_t)(b * T_SEQ + q_glob) * LDQKV + h * HD + hi * 8;
  bf16x8 qfrag[4];
#pragma unroll
  for (int c = 0; c < 4; ++c) {
    bf16x8 raw = *(const bf16x8*)(Qrow + c * 16);
    bf16x8 sc;
#pragma unroll
    for (int j = 0; j < 8; ++j)
      sc[j] = (__bf16)((float)raw[j] * SCALE_LOG2);
    qfrag[c] = sc;
  }

  // all-ones A fragment for the l-row MFMA
  union ob { unsigned u[4]; bf16x8 v; } onesf;
#pragma unroll
  for (int i = 0; i < 4; ++i) onesf.u[i] = 0x3F803F80u;

  f32x16 acc0, acc1, accL, zro;
#pragma unroll
  for (int i = 0; i < 16; ++i) { acc0[i] = 0.f; acc1[i] = 0.f; accL[i] = 0.f; zro[i] = 0.f; }
  float m_run = -1e30f;

  // prologue: load + write tile 0
  int4 kreg[4], vreg[4];
#pragma unroll
  for (int j = 0; j < 4; ++j) { kreg[j] = *(const int4*)gKp[j]; vreg[j] = *(const int4*)gVp[j]; }
#pragma unroll
  for (int j = 0; j < 4; ++j) { lds[kwi[j]] = kreg[j]; lds[vwi[j]] = vreg[j]; }

  for (int t = 0; t < nt; ++t) {
    const int k0 = t << 5;
    const bool masked = (t == nt - 1);
    const bool more = (t + 1 < nt);

    // read this tile's fragments (lgkmcnt ordering vs writes is automatic)
    bf16x8 kf0 = *(const bf16x8*)&lds[kridx[0]];
    bf16x8 kf1 = *(const bf16x8*)&lds[kridx[1]];
    bf16x8 kf2 = *(const bf16x8*)&lds[kridx[2]];
    bf16x8 kf3 = *(const bf16x8*)&lds[kridx[3]];
    bf16x8 vf0 = *(const bf16x8*)&lds[v0idx];
    bf16x8 vf1 = *(const bf16x8*)&lds[v1idx];
    bf16x8 vf2 = *(const bf16x8*)&lds[v2idx];
    bf16x8 vf3 = *(const bf16x8*)&lds[v3idx];

    // issue next tile's global loads now (latency hides under compute)
    if (more) {
      const size_t kAdv = (size_t)(t + 1) * 32 * LDQKV;
      const int vAdv = (t + 1) * 32;
#pragma unroll
      for (int j = 0; j < 4; ++j) {
        kreg[j] = *(const int4*)(gKp[j] + kAdv);
        vreg[j] = *(const int4*)(gVp[j] + vAdv);
      }
    }

    f32x16 st = __builtin_amdgcn_mfma_f32_32x32x16_bf16(kf0, qfrag[0], zro, 0, 0, 0);
    st = __builtin_amdgcn_mfma_f32_32x32x16_bf16(kf1, qfrag[1], st, 0, 0, 0);
    st = __builtin_amdgcn_mfma_f32_32x32x16_bf16(kf2, qfrag[2], st, 0, 0, 0);
    st = __builtin_amdgcn_mfma_f32_32x32x16_bf16(kf3, qfrag[3], st, 0, 0, 0);

    if (masked) {
#pragma unroll
      for (int rr = 0; rr < 16; ++rr) {
        const int kg = k0 + (rr & 3) + 8 * (rr >> 2) + 4 * hi;
        if (kg > q_glob) st[rr] = -1e30f;
      }
    }
    float m01 = fmaxf(fmaxf(st[0], st[1]), st[2]);
    float m02 = fmaxf(fmaxf(st[3], st[4]), st[5]);
    float m03 = fmaxf(fmaxf(st[6], st[7]), st[8]);
    float m04 = fmaxf(fmaxf(st[9], st[10]), st[11]);
    float m05 = fmaxf(fmaxf(st[12], st[13]), st[14]);
    float m06 = fmaxf(fmaxf(m01, m02), m03);
    float m07 = fmaxf(fmaxf(m04, m05), st[15]);
    const float bmax = fmaxf(m06, m07);
    if (__any(bmax > m_run + 8.f)) {        // T13 defer-max
      const float rmax = fmaxf(bmax, __shfl_xor(bmax, 32));
      const float mnew = fmaxf(m_run, rmax);
      const float corr = fexp2(m_run - mnew);
#pragma unroll
      for (int i = 0; i < 16; ++i) { acc0[i] *= corr; acc1[i] *= corr; }
      accL[0] *= corr;
      m_run = mnew;
    }
    float pp[16];
#pragma unroll
    for (int rr = 0; rr < 16; ++rr) pp[rr] = fexp2(st[rr] - m_run);

    // pack P^T B-fragments: HW cvt_pk + permlane32_swap
    unsigned w[8];
#pragma unroll
    for (int i = 0; i < 8; ++i) w[i] = cvtpk(pp[2 * i], pp[2 * i + 1]);
    plswap(w[0], w[2]); plswap(w[1], w[3]);
    plswap(w[4], w[6]); plswap(w[5], w[7]);
    union fu { unsigned u[4]; bf16x8 v; };
    fu f1, f2;
    f1.u[0] = w[0]; f1.u[1] = w[1]; f1.u[2] = w[2]; f1.u[3] = w[3];
    f2.u[0] = w[4]; f2.u[1] = w[5]; f2.u[2] = w[6]; f2.u[3] = w[7];

    acc0 = __builtin_amdgcn_mfma_f32_32x32x16_bf16(vf0, f1.v, acc0, 0, 0, 0);
    acc0 = __builtin_amdgcn_mfma_f32_32x32x16_bf16(vf1, f2.v, acc0, 0, 0, 0);
    acc1 = __builtin_amdgcn_mfma_f32_32x32x16_bf16(vf2, f1.v, acc1, 0, 0, 0);
    acc1 = __builtin_amdgcn_mfma_f32_32x32x16_bf16(vf3, f2.v, acc1, 0, 0, 0);
    accL = __builtin_amdgcn_mfma_f32_32x32x16_bf16(onesf.v, f1.v, accL, 0, 0, 0);
    accL = __builtin_amdgcn_mfma_f32_32x32x16_bf16(onesf.v, f2.v, accL, 0, 0, 0);

    // write next tile (DS pipe in-order: executes after this tile's reads)
    if (more) {
#pragma unroll
      for (int j = 0; j < 4; ++j) { lds[kwi[j]] = kreg[j]; lds[vwi[j]] = vreg[j]; }
    }
  }

  // epilogue: O = acc / l  (l = accL[0], identical across half-lanes)
  const float inv = 1.f / accL[0];
  bf16_t* yrow = y + (size_t)(b * T_SEQ + q_glob) * D_MODEL + h * HD;
#pragma unroll
  for (int gg = 0; gg < 4; ++gg) {
    uint2 o0, o1;
    o0.x = cvtpk(acc0[4 * gg + 0] * inv, acc0[4 * gg + 1] * inv);
    o0.y = cvtpk(acc0[4 * gg + 2] * inv, acc0[4 * gg + 3] * inv);
    o1.x = cvtpk(acc1[4 * gg + 0] * inv, acc1[4 * gg + 1] * inv);
    o1.y = cvtpk(acc1[4 * gg + 2] * inv, acc1[4 * gg + 3] * inv);
    *(uint2*)(yrow + 8 * gg + 4 * hi)      = o0;
    *(uint2*)(yrow + 32 + 8 * gg + 4 * hi) = o1;
  }
}

// ---------------------------------------------------------------------------
extern "C" void kernel_launch(void* const* d_in, const int* in_sizes, int n_in,
                              void* d_out, int out_size, void* d_ws,
                              size_t ws_size, hipStream_t stream) {
  const float* x    = (const float*)d_in[0];
  const float* cosb = (const float*)d_in[1];
  const float* sinb = (const float*)d_in[2];
  const float* Wq   = (const float*)d_in[3];
  const float* Wk   = (const float*)d_in[4];
  const float* Wv   = (const float*)d_in[5];
  const float* Wo   = (const float*)d_in[6];
  const float* qs   = (const float*)d_in[7];
  const float* ks   = (const float*)d_in[8];
  float* out = (float*)d_out;   // reference output dtype is float32

  char* ws = (char*)d_ws;
  bf16_t* qkv   = (bf16_t*)ws;                       // 25165824 B
  bf16_t* v_t   = (bf16_t*)(ws + 25165824);          // 4194304 B
  bf16_t* y     = (bf16_t*)(ws + 29360128);          // 16777216 B (= xb alias)
  bf16_t* xb    = y;                                 // xb dead before attn writes y
  bf16_t* wqkvb = (bf16_t*)(ws + 46137344);          // 3145728 B
  bf16_t* wob   = (bf16_t*)(ws + 49283072);          // 2097152 B

  to_bf16<<<dim3(2048), 256, 0, stream>>>(x, xb, 524288);
  to_bf16<<<dim3(256),  256, 0, stream>>>(Wq, wqkvb, 65536);
  to_bf16<<<dim3(64),   256, 0, stream>>>(Wk, wqkvb + 1024 * 1024, 16384);
  to_bf16<<<dim3(64),   256, 0, stream>>>(Wv, wqkvb + 1280 * 1024, 16384);
  to_bf16<<<dim3(256),  256, 0, stream>>>(Wo, wob, 65536);

  gemm_bb<bf16_t><<<dim3(12, 64), 256, 0, stream>>>(xb, wqkvb, qkv, LDQKV);
  rms_rope<<<dim3(8192), 256, 0, stream>>>(qkv, cosb, sinb, qs, ks);
  v_transpose<<<dim3(16, 32), 256, 0, stream>>>(qkv, v_t);
  attn<<<dim3(4096), 64, 0, stream>>>(qkv, v_t, y);
  gemm_bb<float><<<dim3(8, 64), 256, 0, stream>>>(y, wob, out, D_MODEL);
}

// Round 13
// 177.140 us; speedup vs baseline: 2.2792x; 2.2792x over previous
//
#include <hip/hip_runtime.h>
#include <hip/hip_bf16.h>
#include <stdint.h>

typedef __attribute__((ext_vector_type(8)))  __bf16 bf16x8;
typedef __attribute__((ext_vector_type(4)))  float  f32x4;
typedef __attribute__((ext_vector_type(16))) float  f32x16;
typedef __hip_bfloat16 bf16_t;

#define T_SEQ 2048
#define D_MODEL 1024
#define N_HEADS 16
#define N_KV 4
#define HD 64
#define LDQKV 1536
#define KDIM 1024

// Convert 16 consecutive fp32 (4x float4) -> 16 bf16 (2x int4)
__device__ inline void cvt16(const float4* __restrict__ g, int4* __restrict__ s) {
  float4 v0 = g[0], v1 = g[1], v2 = g[2], v3 = g[3];
  union { int4 i[2]; __hip_bfloat162 h[8]; } u;
  u.h[0] = __float22bfloat162_rn(make_float2(v0.x, v0.y));
  u.h[1] = __float22bfloat162_rn(make_float2(v0.z, v0.w));
  u.h[2] = __float22bfloat162_rn(make_float2(v1.x, v1.y));
  u.h[3] = __float22bfloat162_rn(make_float2(v1.z, v1.w));
  u.h[4] = __float22bfloat162_rn(make_float2(v2.x, v2.y));
  u.h[5] = __float22bfloat162_rn(make_float2(v2.z, v2.w));
  u.h[6] = __float22bfloat162_rn(make_float2(v3.x, v3.y));
  u.h[7] = __float22bfloat162_rn(make_float2(v3.z, v3.w));
  s[0] = u.i[0]; s[1] = u.i[1];
}

__device__ inline void storeC(bf16_t* p, float v) { *p = __float2bfloat16(v); }
__device__ inline void storeC(float* p, float v) { *p = v; }

// v_permlane32_swap_b32 vdst, vsrc: after plswap(a,b): a={a_L,b_L}, b={a_U,b_U}
__device__ inline void plswap(unsigned& a, unsigned& b) {
  asm volatile("v_permlane32_swap_b32 %0, %1" : "+v"(a), "+v"(b));
}

// HW transcendental exp2 (input already in log2 domain)
__device__ inline float fexp2(float x) {
  float r; asm("v_exp_f32 %0, %1" : "=v"(r) : "v"(x)); return r;
}
// HW packed fp32->bf16 (T12 recipe; no builtin on gfx950)
__device__ inline unsigned cvtpk(float lo, float hi) {
  unsigned r; asm("v_cvt_pk_bf16_f32 %0, %1, %2" : "=v"(r) : "v"(lo), "v"(hi));
  return r;
}

// async global->LDS, 16B per lane; lds dest must be wave-uniform base.
__device__ inline void gll16(const bf16_t* g, bf16_t* l) {
  __builtin_amdgcn_global_load_lds(
      (const __attribute__((address_space(1))) void*)g,
      (__attribute__((address_space(3))) void*)l, 16, 0, 0);
}

// ---------------------------------------------------------------------------
// fp32 -> bf16 bulk convert: thread i handles 16 elements.
// ---------------------------------------------------------------------------
__global__ __launch_bounds__(256) void to_bf16(const float* __restrict__ s,
                                               bf16_t* __restrict__ d,
                                               const int n16) {
  const int i = blockIdx.x * 256 + threadIdx.x;
  if (i < n16) cvt16((const float4*)s + i * 4, (int4*)d + i * 2);
}

// ---------------------------------------------------------------------------
// GEMM bf16 x bf16 (unchanged — passing)
// ---------------------------------------------------------------------------
template <typename CT>
__global__ __launch_bounds__(256) void gemm_bb(
    const bf16_t* __restrict__ A, const bf16_t* __restrict__ W,
    CT* __restrict__ C, const int ldC)
{
  __shared__ bf16_t As[128 * 32];
  __shared__ bf16_t Bs[128 * 32];
  const int tid = threadIdx.x;
  const int lane = tid & 63;
  const int wv = tid >> 6;
  const int wr = wv >> 1, wc = wv & 1;
  const int m0 = blockIdx.y * 128;
  const int n0 = blockIdx.x * 128;

  const int srow = lane >> 2;
  const int scol = (lane & 3) * 8;
  const bf16_t* gA = A + (size_t)(m0 + 32 * wv + srow) * KDIM + scol;
  const bf16_t* gB = W + (size_t)(n0 + 32 * wv + srow) * KDIM + scol;
  bf16_t* lA = As + wv * 1024;
  bf16_t* lB = Bs + wv * 1024;

  f32x4 acc[4][4];
#pragma unroll
  for (int m = 0; m < 4; ++m)
#pragma unroll
    for (int n = 0; n < 4; ++n)
      acc[m][n] = {0.f, 0.f, 0.f, 0.f};

  const int fr = lane & 15;
  const int fq = lane >> 4;

  for (int k0 = 0; k0 < KDIM; k0 += 32) {
    gll16(gA + k0, lA);
    gll16(gA + 16 * KDIM + k0, lA + 512);
    gll16(gB + k0, lB);
    gll16(gB + 16 * KDIM + k0, lB + 512);
    __syncthreads();
    bf16x8 af[4], bfv[4];
#pragma unroll
    for (int m = 0; m < 4; ++m)
      af[m] = *(const bf16x8*)(&As[(wr * 64 + m * 16 + fr) * 32 + fq * 8]);
#pragma unroll
    for (int n = 0; n < 4; ++n)
      bfv[n] = *(const bf16x8*)(&Bs[(wc * 64 + n * 16 + fr) * 32 + fq * 8]);
#pragma unroll
    for (int m = 0; m < 4; ++m)
#pragma unroll
      for (int n = 0; n < 4; ++n)
        acc[m][n] = __builtin_amdgcn_mfma_f32_16x16x32_bf16(af[m], bfv[n],
                                                            acc[m][n], 0, 0, 0);
    __syncthreads();
  }

#pragma unroll
  for (int m = 0; m < 4; ++m)
#pragma unroll
    for (int n = 0; n < 4; ++n)
#pragma unroll
      for (int r = 0; r < 4; ++r) {
        const int row = wr * 64 + m * 16 + fq * 4 + r;
        const int col = wc * 64 + n * 16 + fr;
        storeC(&C[(size_t)(m0 + row) * ldC + n0 + col], acc[m][n][r]);
      }
}

// ---------------------------------------------------------------------------
// RMSNorm + RoPE (unchanged — passing)
// ---------------------------------------------------------------------------
__global__ __launch_bounds__(256) void rms_rope(
    bf16_t* __restrict__ qkv, const float* __restrict__ cosb,
    const float* __restrict__ sinb, const float* __restrict__ qs,
    const float* __restrict__ ks)
{
  const int row = blockIdx.x;
  const int t = row & (T_SEQ - 1);
  const int tid = threadIdx.x;
  const int lane = tid & 63;
  const int wv = tid >> 6;
  const int f = lane & 15;
  const float c = (lane < 32) ? cosb[t * 16 + f] : 0.f;
  const float s = (lane < 32) ? sinb[t * 16 + f] : 0.f;
  for (int hh = wv; hh < 20; hh += 4) {
    const size_t idx = (size_t)row * LDQKV + hh * 64 + lane;
    const float v = __bfloat162float(qkv[idx]);
    float ssum = v * v;
#pragma unroll
    for (int off = 32; off; off >>= 1) ssum += __shfl_xor(ssum, off);
    const float norm = rsqrtf(ssum * (1.f / 64.f) + 1e-6f);
    const float scale = (hh < 16 ? qs : ks)[lane];
    float val = v * norm * scale;
    const float partner = __shfl_xor(val, 16);
    if (lane < 16)      val = val * c - partner * s;
    else if (lane < 32) val = partner * s + val * c;
    qkv[idx] = __float2bfloat16(val);
  }
}

// ---------------------------------------------------------------------------
// V transpose (unchanged — passing)
// ---------------------------------------------------------------------------
__global__ __launch_bounds__(256) void v_transpose(
    const bf16_t* __restrict__ qkv, bf16_t* __restrict__ v_t)
{
  __shared__ bf16_t tile[64 * 72];
  const int g = blockIdx.x;
  const int t0 = blockIdx.y * 64;
  const int tid = threadIdx.x;
  const int i = tid >> 2;
  const int dc = (tid & 3) * 16;
  const bf16_t* src = qkv + (size_t)((g >> 2) * T_SEQ + t0 + i) * LDQKV
                      + 1280 + (g & 3) * HD + dc;
  const int4* gs = (const int4*)src;
  int4 x0 = gs[0], x1 = gs[1];
  int4* st = (int4*)(&tile[i * 72 + dc]);
  st[0] = x0; st[1] = x1;
  __syncthreads();
  union { int4 v[2]; bf16_t h[16]; } u;
#pragma unroll
  for (int j = 0; j < 16; ++j) u.h[j] = tile[(dc + j) * 72 + i];
  int4* dst = (int4*)(v_t + (size_t)(g * HD + i) * T_SEQ + t0 + dc);
  dst[0] = u.v[0]; dst[1] = u.v[1];
}

// ---------------------------------------------------------------------------
// Causal GQA flash attention v10 — v8 (4-wave cooperative staging, VALU-diet,
// balanced sb permutation) with KVBLK=64: TWO 32-k subtiles per barrier
// round. Halves the per-round fixed cost (barrier sync + staging handshake).
// LDS 32KB: dbuf x (K 8KB + V 8KB); subtile u at +256 int4 within each half.
// ---------------------------------------------------------------------------
__global__ __launch_bounds__(256) void attn(
    const bf16_t* __restrict__ qkv, const bf16_t* __restrict__ v_t,
    bf16_t* __restrict__ y)
{
  __shared__ int4 lds[2048];      // 32 KB
  const int tid  = threadIdx.x;
  const int lane = tid & 63;
  const int wv   = tid >> 6;
  const int ql   = lane & 31;
  const int hi   = lane >> 5;
  const int id   = (int)blockIdx.x;          // 0..1023
  const int low3 = id & 7;
  const int rest = id >> 3;
  const int gsel = rest & 1;
  const int hh   = (rest >> 1) & 3;
  const int sbi  = rest >> 3;                // 0..15
  // balanced permutation: CU class {m,m+4,m+8,m+12} -> sb sums of 30 each.
  const int sb   = ((sbi >> 2) & 1) ? (sbi + 4 - ((sbi >> 3) << 4)) : (15 - sbi);
  const int g16  = low3 + 8 * gsel;          // b*4+kvh
  const int b    = g16 >> 2, kvh = g16 & 3;
  const int h    = kvh * 4 + hh;
  const int s    = sb * 4 + wv;
  const int q_glob = s * 32 + ql;
  const int nt     = s + 1;                  // 32-k tiles (last = diagonal)
  const int nR     = 2 * sb + 2;             // 64-k rounds (block-uniform)
  const float SCALE_LOG2 = 0.125f * 1.44269504089f;

  // staging addresses (per 32-k subtile; advance by k0 externally)
  const int kr = tid >> 3, kslot = tid & 7;
  const int vd = tid >> 2, vslot = tid & 3;
  const bf16_t* gK = qkv + (size_t)(b * T_SEQ + kr) * LDQKV + 1024 + kvh * HD + kslot * 8;
  const bf16_t* gV = v_t + (size_t)((b * N_KV + kvh) * HD + vd) * T_SEQ + vslot * 8;
  const int wKidx = kr * 8 + (kslot ^ (kr & 7));            // + u*256 + buf*1024
  const int wVidx = 512 + vd * 4 + (vslot ^ ((vd >> 1) & 3)); // + u*256 + buf*1024

  // fragment read indices (per subtile; + u*256 + buf*1024)
  int kridx[4];
#pragma unroll
  for (int c = 0; c < 4; ++c)
    kridx[c] = ql * 8 + ((2 * c + hi) ^ (ql & 7));
  const int vsw = (ql >> 1) & 3;
  const int v0idx = 512 + ql * 4 + (hi ^ vsw);
  const int v1idx = 512 + ql * 4 + ((2 + hi) ^ vsw);
  const int v2idx = 512 + (ql + 32) * 4 + (hi ^ vsw);
  const int v3idx = 512 + (ql + 32) * 4 + ((2 + hi) ^ vsw);

  // Q fragments, pre-scaled into log2 domain
  const bf16_t* Qrow = qkv + (size_t)(b * T_SEQ + q_glob) * LDQKV + h * HD + hi * 8;
  bf16x8 qfrag[4];
#pragma unroll
  for (int c = 0; c < 4; ++c) {
    bf16x8 raw = *(const bf16x8*)(Qrow + c * 16);
    bf16x8 sc;
#pragma unroll
    for (int j = 0; j < 8; ++j)
      sc[j] = (__bf16)((float)raw[j] * SCALE_LOG2);
    qfrag[c] = sc;
  }

  // all-ones A fragment for the l-row MFMA
  union ob { unsigned u[4]; bf16x8 v; } onesf;
#pragma unroll
  for (int i = 0; i < 4; ++i) onesf.u[i] = 0x3F803F80u;

  f32x16 acc0, acc1, accL, zro;
#pragma unroll
  for (int i = 0; i < 16; ++i) { acc0[i] = 0.f; acc1[i] = 0.f; accL[i] = 0.f; zro[i] = 0.f; }
  float m_run = -1e30f;

  // prologue: stage round-0 pair (subtiles 0,1) into buf 0
  {
    int4 kA = *(const int4*)gK;
    int4 vA = *(const int4*)gV;
    int4 kB = *(const int4*)(gK + (size_t)32 * LDQKV);
    int4 vB = *(const int4*)(gV + 32);
    lds[wKidx] = kA;       lds[wVidx] = vA;
    lds[256 + wKidx] = kB; lds[256 + wVidx] = vB;
  }
  __syncthreads();

  int buf = 0;
  for (int r = 0; r < nR; ++r) {
    // issue next round's staging loads early
    int4 kA, vA, kB, vB;
    const bool more = (r + 1 < nR);
    if (more) {
      const size_t kAdv = (size_t)(r + 1) * 64 * LDQKV;
      const int vAdv = (r + 1) * 64;
      kA = *(const int4*)(gK + kAdv);
      vA = *(const int4*)(gV + vAdv);
      kB = *(const int4*)(gK + kAdv + (size_t)32 * LDQKV);
      vB = *(const int4*)(gV + vAdv + 32);
    }

#pragma unroll
    for (int u = 0; u < 2; ++u) {
      const int t = 2 * r + u;
      if (t < nt) {
        const int k0 = t << 5;
        const bool masked = (t == nt - 1);
        const int base = buf * 1024 + u * 256;

        bf16x8 kf0 = *(const bf16x8*)&lds[base + kridx[0]];
        bf16x8 kf1 = *(const bf16x8*)&lds[base + kridx[1]];
        bf16x8 kf2 = *(const bf16x8*)&lds[base + kridx[2]];
        bf16x8 kf3 = *(const bf16x8*)&lds[base + kridx[3]];

        f32x16 st = __builtin_amdgcn_mfma_f32_32x32x16_bf16(kf0, qfrag[0], zro, 0, 0, 0);
        st = __builtin_amdgcn_mfma_f32_32x32x16_bf16(kf1, qfrag[1], st, 0, 0, 0);
        st = __builtin_amdgcn_mfma_f32_32x32x16_bf16(kf2, qfrag[2], st, 0, 0, 0);
        st = __builtin_amdgcn_mfma_f32_32x32x16_bf16(kf3, qfrag[3], st, 0, 0, 0);

        if (masked) {
#pragma unroll
          for (int rr = 0; rr < 16; ++rr) {
            const int kg = k0 + (rr & 3) + 8 * (rr >> 2) + 4 * hi;
            if (kg > q_glob) st[rr] = -1e30f;
          }
        }
        float m01 = fmaxf(fmaxf(st[0], st[1]), st[2]);
        float m02 = fmaxf(fmaxf(st[3], st[4]), st[5]);
        float m03 = fmaxf(fmaxf(st[6], st[7]), st[8]);
        float m04 = fmaxf(fmaxf(st[9], st[10]), st[11]);
        float m05 = fmaxf(fmaxf(st[12], st[13]), st[14]);
        float m06 = fmaxf(fmaxf(m01, m02), m03);
        float m07 = fmaxf(fmaxf(m04, m05), st[15]);
        const float bmax = fmaxf(m06, m07);
        if (__any(bmax > m_run + 8.f)) {        // T13 defer-max
          const float rmax = fmaxf(bmax, __shfl_xor(bmax, 32));
          const float mnew = fmaxf(m_run, rmax);
          const float corr = fexp2(m_run - mnew);
#pragma unroll
          for (int i = 0; i < 16; ++i) { acc0[i] *= corr; acc1[i] *= corr; }
          accL[0] *= corr;
          m_run = mnew;
        }
        float pp[16];
#pragma unroll
        for (int rr = 0; rr < 16; ++rr) pp[rr] = fexp2(st[rr] - m_run);

        unsigned w[8];
#pragma unroll
        for (int i = 0; i < 8; ++i) w[i] = cvtpk(pp[2 * i], pp[2 * i + 1]);
        plswap(w[0], w[2]); plswap(w[1], w[3]);
        plswap(w[4], w[6]); plswap(w[5], w[7]);
        union fu { unsigned u[4]; bf16x8 v; };
        fu f1, f2;
        f1.u[0] = w[0]; f1.u[1] = w[1]; f1.u[2] = w[2]; f1.u[3] = w[3];
        f2.u[0] = w[4]; f2.u[1] = w[5]; f2.u[2] = w[6]; f2.u[3] = w[7];

        bf16x8 vf0 = *(const bf16x8*)&lds[base + v0idx];
        bf16x8 vf1 = *(const bf16x8*)&lds[base + v1idx];
        bf16x8 vf2 = *(const bf16x8*)&lds[base + v2idx];
        bf16x8 vf3 = *(const bf16x8*)&lds[base + v3idx];

        acc0 = __builtin_amdgcn_mfma_f32_32x32x16_bf16(vf0, f1.v, acc0, 0, 0, 0);
        acc0 = __builtin_amdgcn_mfma_f32_32x32x16_bf16(vf1, f2.v, acc0, 0, 0, 0);
        acc1 = __builtin_amdgcn_mfma_f32_32x32x16_bf16(vf2, f1.v, acc1, 0, 0, 0);
        acc1 = __builtin_amdgcn_mfma_f32_32x32x16_bf16(vf3, f2.v, acc1, 0, 0, 0);
        accL = __builtin_amdgcn_mfma_f32_32x32x16_bf16(onesf.v, f1.v, accL, 0, 0, 0);
        accL = __builtin_amdgcn_mfma_f32_32x32x16_bf16(onesf.v, f2.v, accL, 0, 0, 0);
      }
    }

    // write next round's pair into the other buffer
    if (more) {
      const int nb = (buf ^ 1) * 1024;
      lds[nb + wKidx] = kA;       lds[nb + wVidx] = vA;
      lds[nb + 256 + wKidx] = kB; lds[nb + 256 + wVidx] = vB;
    }
    __syncthreads();
    buf ^= 1;
  }

  // epilogue: O = acc / l  (l = accL[0], identical across half-lanes)
  const float inv = 1.f / accL[0];
  bf16_t* yrow = y + (size_t)(b * T_SEQ + q_glob) * D_MODEL + h * HD;
#pragma unroll
  for (int gg = 0; gg < 4; ++gg) {
    uint2 o0, o1;
    o0.x = cvtpk(acc0[4 * gg + 0] * inv, acc0[4 * gg + 1] * inv);
    o0.y = cvtpk(acc0[4 * gg + 2] * inv, acc0[4 * gg + 3] * inv);
    o1.x = cvtpk(acc1[4 * gg + 0] * inv, acc1[4 * gg + 1] * inv);
    o1.y = cvtpk(acc1[4 * gg + 2] * inv, acc1[4 * gg + 3] * inv);
    *(uint2*)(yrow + 8 * gg + 4 * hi)      = o0;
    *(uint2*)(yrow + 32 + 8 * gg + 4 * hi) = o1;
  }
}

// ---------------------------------------------------------------------------
extern "C" void kernel_launch(void* const* d_in, const int* in_sizes, int n_in,
                              void* d_out, int out_size, void* d_ws,
                              size_t ws_size, hipStream_t stream) {
  const float* x    = (const float*)d_in[0];
  const float* cosb = (const float*)d_in[1];
  const float* sinb = (const float*)d_in[2];
  const float* Wq   = (const float*)d_in[3];
  const float* Wk   = (const float*)d_in[4];
  const float* Wv   = (const float*)d_in[5];
  const float* Wo   = (const float*)d_in[6];
  const float* qs   = (const float*)d_in[7];
  const float* ks   = (const float*)d_in[8];
  float* out = (float*)d_out;   // reference output dtype is float32

  char* ws = (char*)d_ws;
  bf16_t* qkv   = (bf16_t*)ws;                       // 25165824 B
  bf16_t* v_t   = (bf16_t*)(ws + 25165824);          // 4194304 B
  bf16_t* y     = (bf16_t*)(ws + 29360128);          // 16777216 B (= xb alias)
  bf16_t* xb    = y;                                 // xb dead before attn writes y
  bf16_t* wqkvb = (bf16_t*)(ws + 46137344);          // 3145728 B
  bf16_t* wob   = (bf16_t*)(ws + 49283072);          // 2097152 B

  to_bf16<<<dim3(2048), 256, 0, stream>>>(x, xb, 524288);
  to_bf16<<<dim3(256),  256, 0, stream>>>(Wq, wqkvb, 65536);
  to_bf16<<<dim3(64),   256, 0, stream>>>(Wk, wqkvb + 1024 * 1024, 16384);
  to_bf16<<<dim3(64),   256, 0, stream>>>(Wv, wqkvb + 1280 * 1024, 16384);
  to_bf16<<<dim3(256),  256, 0, stream>>>(Wo, wob, 65536);

  gemm_bb<bf16_t><<<dim3(12, 64), 256, 0, stream>>>(xb, wqkvb, qkv, LDQKV);
  rms_rope<<<dim3(8192), 256, 0, stream>>>(qkv, cosb, sinb, qs, ks);
  v_transpose<<<dim3(16, 32), 256, 0, stream>>>(qkv, v_t);
  attn<<<dim3(1024), 256, 0, stream>>>(qkv, v_t, y);
  gemm_bb<float><<<dim3(8, 64), 256, 0, stream>>>(y, wob, out, D_MODEL);
}

// Round 14
// 166.652 us; speedup vs baseline: 2.4227x; 1.0629x over previous
//
#include <hip/hip_runtime.h>
#include <hip/hip_bf16.h>
#include <stdint.h>

typedef __attribute__((ext_vector_type(8)))  __bf16 bf16x8;
typedef __attribute__((ext_vector_type(4)))  float  f32x4;
typedef __attribute__((ext_vector_type(16))) float  f32x16;
typedef __hip_bfloat16 bf16_t;

#define T_SEQ 2048
#define D_MODEL 1024
#define N_HEADS 16
#define N_KV 4
#define HD 64
#define LDQKV 1536
#define KDIM 1024

// Convert 16 consecutive fp32 (4x float4) -> 16 bf16 (2x int4)
__device__ inline void cvt16(const float4* __restrict__ g, int4* __restrict__ s) {
  float4 v0 = g[0], v1 = g[1], v2 = g[2], v3 = g[3];
  union { int4 i[2]; __hip_bfloat162 h[8]; } u;
  u.h[0] = __float22bfloat162_rn(make_float2(v0.x, v0.y));
  u.h[1] = __float22bfloat162_rn(make_float2(v0.z, v0.w));
  u.h[2] = __float22bfloat162_rn(make_float2(v1.x, v1.y));
  u.h[3] = __float22bfloat162_rn(make_float2(v1.z, v1.w));
  u.h[4] = __float22bfloat162_rn(make_float2(v2.x, v2.y));
  u.h[5] = __float22bfloat162_rn(make_float2(v2.z, v2.w));
  u.h[6] = __float22bfloat162_rn(make_float2(v3.x, v3.y));
  u.h[7] = __float22bfloat162_rn(make_float2(v3.z, v3.w));
  s[0] = u.i[0]; s[1] = u.i[1];
}

__device__ inline void storeC(bf16_t* p, float v) { *p = __float2bfloat16(v); }
__device__ inline void storeC(float* p, float v) { *p = v; }

// v_permlane32_swap_b32 vdst, vsrc: after plswap(a,b): a={a_L,b_L}, b={a_U,b_U}
__device__ inline void plswap(unsigned& a, unsigned& b) {
  asm volatile("v_permlane32_swap_b32 %0, %1" : "+v"(a), "+v"(b));
}

// HW transcendental exp2 (input already in log2 domain)
__device__ inline float fexp2(float x) {
  float r; asm("v_exp_f32 %0, %1" : "=v"(r) : "v"(x)); return r;
}
// HW packed fp32->bf16 (T12 recipe; no builtin on gfx950)
__device__ inline unsigned cvtpk(float lo, float hi) {
  unsigned r; asm("v_cvt_pk_bf16_f32 %0, %1, %2" : "=v"(r) : "v"(lo), "v"(hi));
  return r;
}

// async global->LDS, 16B per lane; lds dest must be wave-uniform base.
__device__ inline void gll16(const bf16_t* g, bf16_t* l) {
  __builtin_amdgcn_global_load_lds(
      (const __attribute__((address_space(1))) void*)g,
      (__attribute__((address_space(3))) void*)l, 16, 0, 0);
}

// ---------------------------------------------------------------------------
// fp32 -> bf16 bulk converts
// ---------------------------------------------------------------------------
__global__ __launch_bounds__(256) void to_bf16(const float* __restrict__ s,
                                               bf16_t* __restrict__ d,
                                               const int n16) {
  const int i = blockIdx.x * 256 + threadIdx.x;
  if (i < n16) cvt16((const float4*)s + i * 4, (int4*)d + i * 2);
}

// all weights in one launch: [0,64K) Wq->wqkvb, [64K,80K) Wk, [80K,96K) Wv,
// [96K,160K) Wo->wob   (units of 16 elements)
__global__ __launch_bounds__(256) void w_cvt(
    const float* __restrict__ Wq, const float* __restrict__ Wk,
    const float* __restrict__ Wv, const float* __restrict__ Wo,
    bf16_t* __restrict__ wqkvb, bf16_t* __restrict__ wob) {
  const int i = blockIdx.x * 256 + threadIdx.x;
  const float* s; bf16_t* d; int off;
  if (i < 65536)       { s = Wq; d = wqkvb;                off = i; }
  else if (i < 81920)  { s = Wk; d = wqkvb + 1024 * 1024;  off = i - 65536; }
  else if (i < 98304)  { s = Wv; d = wqkvb + 1280 * 1024;  off = i - 81920; }
  else                 { s = Wo; d = wob;                  off = i - 98304; }
  cvt16((const float4*)s + off * 4, (int4*)d + off * 2);
}

// ---------------------------------------------------------------------------
// GEMM bf16 x bf16, m97 structure (128x128, BK=32, global_load_lds w16).
// MODE 0: plain store to C (out-projection).
// MODE 1: fused QKV epilogue — q/k blocks (n0<1280): RMSNorm (fp32, over the
//   64-d head held by wave column wc) + RoPE (lane-local pair n=0/n=1) then
//   bf16 store to qkv; v blocks (n0>=1280): transposed 8B store to v_t.
// ---------------------------------------------------------------------------
template <int MODE, typename CT>
__global__ __launch_bounds__(256) void gemm_bb(
    const bf16_t* __restrict__ A, const bf16_t* __restrict__ W,
    CT* __restrict__ C, const int ldC,
    const float* __restrict__ cosb, const float* __restrict__ sinb,
    const float* __restrict__ qs, const float* __restrict__ ks,
    bf16_t* __restrict__ v_t)
{
  __shared__ bf16_t As[128 * 32];
  __shared__ bf16_t Bs[128 * 32];
  const int tid = threadIdx.x;
  const int lane = tid & 63;
  const int wv = tid >> 6;
  const int wr = wv >> 1, wc = wv & 1;
  const int m0 = blockIdx.y * 128;
  const int n0 = blockIdx.x * 128;

  const int srow = lane >> 2;
  const int scol = (lane & 3) * 8;
  const bf16_t* gA = A + (size_t)(m0 + 32 * wv + srow) * KDIM + scol;
  const bf16_t* gB = W + (size_t)(n0 + 32 * wv + srow) * KDIM + scol;
  bf16_t* lA = As + wv * 1024;
  bf16_t* lB = Bs + wv * 1024;

  f32x4 acc[4][4];
#pragma unroll
  for (int m = 0; m < 4; ++m)
#pragma unroll
    for (int n = 0; n < 4; ++n)
      acc[m][n] = {0.f, 0.f, 0.f, 0.f};

  const int fr = lane & 15;
  const int fq = lane >> 4;

  for (int k0 = 0; k0 < KDIM; k0 += 32) {
    gll16(gA + k0, lA);
    gll16(gA + 16 * KDIM + k0, lA + 512);
    gll16(gB + k0, lB);
    gll16(gB + 16 * KDIM + k0, lB + 512);
    __syncthreads();
    bf16x8 af[4], bfv[4];
#pragma unroll
    for (int m = 0; m < 4; ++m)
      af[m] = *(const bf16x8*)(&As[(wr * 64 + m * 16 + fr) * 32 + fq * 8]);
#pragma unroll
    for (int n = 0; n < 4; ++n)
      bfv[n] = *(const bf16x8*)(&Bs[(wc * 64 + n * 16 + fr) * 32 + fq * 8]);
#pragma unroll
    for (int m = 0; m < 4; ++m)
#pragma unroll
      for (int n = 0; n < 4; ++n)
        acc[m][n] = __builtin_amdgcn_mfma_f32_16x16x32_bf16(af[m], bfv[n],
                                                            acc[m][n], 0, 0, 0);
    __syncthreads();
  }

  if (MODE == 0 || n0 < 1280) {
    if (MODE == 1) {
      // q/k: RMSNorm + RoPE fused (fp32), then bf16 store
      const float* stab = (n0 < 1024) ? qs : ks;
      float sc0 = stab[fr], sc1 = stab[16 + fr], sc2 = stab[32 + fr], sc3 = stab[48 + fr];
#pragma unroll
      for (int m = 0; m < 4; ++m)
#pragma unroll
        for (int r = 0; r < 4; ++r) {
          const int row = m0 + wr * 64 + m * 16 + fq * 4 + r;
          const int t = row & (T_SEQ - 1);
          float ss = acc[m][0][r] * acc[m][0][r] + acc[m][1][r] * acc[m][1][r]
                   + acc[m][2][r] * acc[m][2][r] + acc[m][3][r] * acc[m][3][r];
          ss += __shfl_xor(ss, 1);
          ss += __shfl_xor(ss, 2);
          ss += __shfl_xor(ss, 4);
          ss += __shfl_xor(ss, 8);
          const float nrm = rsqrtf(ss * (1.f / 64.f) + 1e-6f);
          const float v0 = acc[m][0][r] * nrm * sc0;
          const float v1 = acc[m][1][r] * nrm * sc1;
          const float v2 = acc[m][2][r] * nrm * sc2;
          const float v3 = acc[m][3][r] * nrm * sc3;
          const float c = cosb[t * 16 + fr];
          const float s = sinb[t * 16 + fr];
          const float r0 = v0 * c - v1 * s;
          const float r1 = v0 * s + v1 * c;
          bf16_t* p = (bf16_t*)C + (size_t)row * ldC + n0 + wc * 64 + fr;
          p[0]  = __float2bfloat16(r0);
          p[16] = __float2bfloat16(r1);
          p[32] = __float2bfloat16(v2);
          p[48] = __float2bfloat16(v3);
        }
    } else {
#pragma unroll
      for (int m = 0; m < 4; ++m)
#pragma unroll
        for (int n = 0; n < 4; ++n)
#pragma unroll
          for (int r = 0; r < 4; ++r) {
            const int row = wr * 64 + m * 16 + fq * 4 + r;
            const int col = wc * 64 + n * 16 + fr;
            storeC(&C[(size_t)(m0 + row) * ldC + n0 + col], acc[m][n][r]);
          }
    }
  } else {
    // v blocks: transposed store to v_t[(b*4+kvh)*64 + d][t]
#pragma unroll
    for (int m = 0; m < 4; ++m) {
      const int row0 = m0 + wr * 64 + m * 16 + fq * 4;   // r = 0..3 consecutive t
      const int b = row0 >> 11, t0 = row0 & (T_SEQ - 1);
#pragma unroll
      for (int n = 0; n < 4; ++n) {
        const int vcol = n0 - 1280 + wc * 64 + n * 16 + fr;
        const int g = b * 4 + (vcol >> 6);
        const int d = vcol & 63;
        uint2 pk2;
        pk2.x = cvtpk(acc[m][n][0], acc[m][n][1]);
        pk2.y = cvtpk(acc[m][n][2], acc[m][n][3]);
        *(uint2*)(v_t + ((size_t)g * HD + d) * T_SEQ + t0) = pk2;
      }
    }
  }
}

// ---------------------------------------------------------------------------
// Causal GQA flash attention v10 (unchanged from round 13 — passing, 89.7us)
// ---------------------------------------------------------------------------
__global__ __launch_bounds__(256) void attn(
    const bf16_t* __restrict__ qkv, const bf16_t* __restrict__ v_t,
    bf16_t* __restrict__ y)
{
  __shared__ int4 lds[2048];      // 32 KB
  const int tid  = threadIdx.x;
  const int lane = tid & 63;
  const int wv   = tid >> 6;
  const int ql   = lane & 31;
  const int hi   = lane >> 5;
  const int id   = (int)blockIdx.x;          // 0..1023
  const int low3 = id & 7;
  const int rest = id >> 3;
  const int gsel = rest & 1;
  const int hh   = (rest >> 1) & 3;
  const int sbi  = rest >> 3;                // 0..15
  const int sb   = ((sbi >> 2) & 1) ? (sbi + 4 - ((sbi >> 3) << 4)) : (15 - sbi);
  const int g16  = low3 + 8 * gsel;          // b*4+kvh
  const int b    = g16 >> 2, kvh = g16 & 3;
  const int h    = kvh * 4 + hh;
  const int s    = sb * 4 + wv;
  const int q_glob = s * 32 + ql;
  const int nt     = s + 1;
  const int nR     = 2 * sb + 2;
  const float SCALE_LOG2 = 0.125f * 1.44269504089f;

  const int kr = tid >> 3, kslot = tid & 7;
  const int vd = tid >> 2, vslot = tid & 3;
  const bf16_t* gK = qkv + (size_t)(b * T_SEQ + kr) * LDQKV + 1024 + kvh * HD + kslot * 8;
  const bf16_t* gV = v_t + (size_t)((b * N_KV + kvh) * HD + vd) * T_SEQ + vslot * 8;
  const int wKidx = kr * 8 + (kslot ^ (kr & 7));
  const int wVidx = 512 + vd * 4 + (vslot ^ ((vd >> 1) & 3));

  int kridx[4];
#pragma unroll
  for (int c = 0; c < 4; ++c)
    kridx[c] = ql * 8 + ((2 * c + hi) ^ (ql & 7));
  const int vsw = (ql >> 1) & 3;
  const int v0idx = 512 + ql * 4 + (hi ^ vsw);
  const int v1idx = 512 + ql * 4 + ((2 + hi) ^ vsw);
  const int v2idx = 512 + (ql + 32) * 4 + (hi ^ vsw);
  const int v3idx = 512 + (ql + 32) * 4 + ((2 + hi) ^ vsw);

  const bf16_t* Qrow = qkv + (size_t)(b * T_SEQ + q_glob) * LDQKV + h * HD + hi * 8;
  bf16x8 qfrag[4];
#pragma unroll
  for (int c = 0; c < 4; ++c) {
    bf16x8 raw = *(const bf16x8*)(Qrow + c * 16);
    bf16x8 sc;
#pragma unroll
    for (int j = 0; j < 8; ++j)
      sc[j] = (__bf16)((float)raw[j] * SCALE_LOG2);
    qfrag[c] = sc;
  }

  union ob { unsigned u[4]; bf16x8 v; } onesf;
#pragma unroll
  for (int i = 0; i < 4; ++i) onesf.u[i] = 0x3F803F80u;

  f32x16 acc0, acc1, accL, zro;
#pragma unroll
  for (int i = 0; i < 16; ++i) { acc0[i] = 0.f; acc1[i] = 0.f; accL[i] = 0.f; zro[i] = 0.f; }
  float m_run = -1e30f;

  {
    int4 kA = *(const int4*)gK;
    int4 vA = *(const int4*)gV;
    int4 kB = *(const int4*)(gK + (size_t)32 * LDQKV);
    int4 vB = *(const int4*)(gV + 32);
    lds[wKidx] = kA;       lds[wVidx] = vA;
    lds[256 + wKidx] = kB; lds[256 + wVidx] = vB;
  }
  __syncthreads();

  int buf = 0;
  for (int r = 0; r < nR; ++r) {
    int4 kA, vA, kB, vB;
    const bool more = (r + 1 < nR);
    if (more) {
      const size_t kAdv = (size_t)(r + 1) * 64 * LDQKV;
      const int vAdv = (r + 1) * 64;
      kA = *(const int4*)(gK + kAdv);
      vA = *(const int4*)(gV + vAdv);
      kB = *(const int4*)(gK + kAdv + (size_t)32 * LDQKV);
      vB = *(const int4*)(gV + vAdv + 32);
    }

#pragma unroll
    for (int u = 0; u < 2; ++u) {
      const int t = 2 * r + u;
      if (t < nt) {
        const int k0 = t << 5;
        const bool masked = (t == nt - 1);
        const int base = buf * 1024 + u * 256;

        bf16x8 kf0 = *(const bf16x8*)&lds[base + kridx[0]];
        bf16x8 kf1 = *(const bf16x8*)&lds[base + kridx[1]];
        bf16x8 kf2 = *(const bf16x8*)&lds[base + kridx[2]];
        bf16x8 kf3 = *(const bf16x8*)&lds[base + kridx[3]];

        f32x16 st = __builtin_amdgcn_mfma_f32_32x32x16_bf16(kf0, qfrag[0], zro, 0, 0, 0);
        st = __builtin_amdgcn_mfma_f32_32x32x16_bf16(kf1, qfrag[1], st, 0, 0, 0);
        st = __builtin_amdgcn_mfma_f32_32x32x16_bf16(kf2, qfrag[2], st, 0, 0, 0);
        st = __builtin_amdgcn_mfma_f32_32x32x16_bf16(kf3, qfrag[3], st, 0, 0, 0);

        if (masked) {
#pragma unroll
          for (int rr = 0; rr < 16; ++rr) {
            const int kg = k0 + (rr & 3) + 8 * (rr >> 2) + 4 * hi;
            if (kg > q_glob) st[rr] = -1e30f;
          }
        }
        float m01 = fmaxf(fmaxf(st[0], st[1]), st[2]);
        float m02 = fmaxf(fmaxf(st[3], st[4]), st[5]);
        float m03 = fmaxf(fmaxf(st[6], st[7]), st[8]);
        float m04 = fmaxf(fmaxf(st[9], st[10]), st[11]);
        float m05 = fmaxf(fmaxf(st[12], st[13]), st[14]);
        float m06 = fmaxf(fmaxf(m01, m02), m03);
        float m07 = fmaxf(fmaxf(m04, m05), st[15]);
        const float bmax = fmaxf(m06, m07);
        if (__any(bmax > m_run + 8.f)) {        // T13 defer-max
          const float rmax = fmaxf(bmax, __shfl_xor(bmax, 32));
          const float mnew = fmaxf(m_run, rmax);
          const float corr = fexp2(m_run - mnew);
#pragma unroll
          for (int i = 0; i < 16; ++i) { acc0[i] *= corr; acc1[i] *= corr; }
          accL[0] *= corr;
          m_run = mnew;
        }
        float pp[16];
#pragma unroll
        for (int rr = 0; rr < 16; ++rr) pp[rr] = fexp2(st[rr] - m_run);

        unsigned w[8];
#pragma unroll
        for (int i = 0; i < 8; ++i) w[i] = cvtpk(pp[2 * i], pp[2 * i + 1]);
        plswap(w[0], w[2]); plswap(w[1], w[3]);
        plswap(w[4], w[6]); plswap(w[5], w[7]);
        union fu { unsigned u[4]; bf16x8 v; };
        fu f1, f2;
        f1.u[0] = w[0]; f1.u[1] = w[1]; f1.u[2] = w[2]; f1.u[3] = w[3];
        f2.u[0] = w[4]; f2.u[1] = w[5]; f2.u[2] = w[6]; f2.u[3] = w[7];

        bf16x8 vf0 = *(const bf16x8*)&lds[base + v0idx];
        bf16x8 vf1 = *(const bf16x8*)&lds[base + v1idx];
        bf16x8 vf2 = *(const bf16x8*)&lds[base + v2idx];
        bf16x8 vf3 = *(const bf16x8*)&lds[base + v3idx];

        acc0 = __builtin_amdgcn_mfma_f32_32x32x16_bf16(vf0, f1.v, acc0, 0, 0, 0);
        acc0 = __builtin_amdgcn_mfma_f32_32x32x16_bf16(vf1, f2.v, acc0, 0, 0, 0);
        acc1 = __builtin_amdgcn_mfma_f32_32x32x16_bf16(vf2, f1.v, acc1, 0, 0, 0);
        acc1 = __builtin_amdgcn_mfma_f32_32x32x16_bf16(vf3, f2.v, acc1, 0, 0, 0);
        accL = __builtin_amdgcn_mfma_f32_32x32x16_bf16(onesf.v, f1.v, accL, 0, 0, 0);
        accL = __builtin_amdgcn_mfma_f32_32x32x16_bf16(onesf.v, f2.v, accL, 0, 0, 0);
      }
    }

    if (more) {
      const int nb = (buf ^ 1) * 1024;
      lds[nb + wKidx] = kA;       lds[nb + wVidx] = vA;
      lds[nb + 256 + wKidx] = kB; lds[nb + 256 + wVidx] = vB;
    }
    __syncthreads();
    buf ^= 1;
  }

  const float inv = 1.f / accL[0];
  bf16_t* yrow = y + (size_t)(b * T_SEQ + q_glob) * D_MODEL + h * HD;
#pragma unroll
  for (int gg = 0; gg < 4; ++gg) {
    uint2 o0, o1;
    o0.x = cvtpk(acc0[4 * gg + 0] * inv, acc0[4 * gg + 1] * inv);
    o0.y = cvtpk(acc0[4 * gg + 2] * inv, acc0[4 * gg + 3] * inv);
    o1.x = cvtpk(acc1[4 * gg + 0] * inv, acc1[4 * gg + 1] * inv);
    o1.y = cvtpk(acc1[4 * gg + 2] * inv, acc1[4 * gg + 3] * inv);
    *(uint2*)(yrow + 8 * gg + 4 * hi)      = o0;
    *(uint2*)(yrow + 32 + 8 * gg + 4 * hi) = o1;
  }
}

// ---------------------------------------------------------------------------
extern "C" void kernel_launch(void* const* d_in, const int* in_sizes, int n_in,
                              void* d_out, int out_size, void* d_ws,
                              size_t ws_size, hipStream_t stream) {
  const float* x    = (const float*)d_in[0];
  const float* cosb = (const float*)d_in[1];
  const float* sinb = (const float*)d_in[2];
  const float* Wq   = (const float*)d_in[3];
  const float* Wk   = (const float*)d_in[4];
  const float* Wv   = (const float*)d_in[5];
  const float* Wo   = (const float*)d_in[6];
  const float* qs   = (const float*)d_in[7];
  const float* ks   = (const float*)d_in[8];
  float* out = (float*)d_out;   // reference output dtype is float32

  char* ws = (char*)d_ws;
  bf16_t* qkv   = (bf16_t*)ws;                       // 25165824 B
  bf16_t* v_t   = (bf16_t*)(ws + 25165824);          // 4194304 B
  bf16_t* y     = (bf16_t*)(ws + 29360128);          // 16777216 B (= xb alias)
  bf16_t* xb    = y;                                 // xb dead before attn writes y
  bf16_t* wqkvb = (bf16_t*)(ws + 46137344);          // 3145728 B
  bf16_t* wob   = (bf16_t*)(ws + 49283072);          // 2097152 B

  // 0. fp32 -> bf16 converts (2 launches)
  to_bf16<<<dim3(2048), 256, 0, stream>>>(x, xb, 524288);
  w_cvt<<<dim3(640), 256, 0, stream>>>(Wq, Wk, Wv, Wo, wqkvb, wob);

  // 1. fused QKV projection + RMSNorm + RoPE + V-transpose (epilogue-fused)
  gemm_bb<1, bf16_t><<<dim3(12, 64), 256, 0, stream>>>(
      xb, wqkvb, qkv, LDQKV, cosb, sinb, qs, ks, v_t);
  // 2. causal GQA flash attention -> y
  attn<<<dim3(1024), 256, 0, stream>>>(qkv, v_t, y);
  // 3. output projection
  gemm_bb<0, float><<<dim3(8, 64), 256, 0, stream>>>(
      y, wob, out, D_MODEL, nullptr, nullptr, nullptr, nullptr, nullptr);
}